// Round 19
// baseline (81.087 us; speedup 1.0000x reference)
//
#include <hip/hip_runtime.h>

#define N_NODES 100000
#define N_EDGES 320000
#define Q 4096
#define HID 128
#define DIN 256
#define EMB_LD 260      // DIN + 4 pad
#define NSLOT (3 * Q)   // 12288
#define CAP 64
#define QPB 8
#define KT 32           // k-tile staged in LDS

// ---------------- K1: slot = -1 ----------------
__global__ __launch_bounds__(256) void k_init(int4* __restrict__ slot4) {
    int i = blockIdx.x * 256 + threadIdx.x;
    if (i < N_NODES / 4) slot4[i] = make_int4(-1, -1, -1, -1);
}

// ---------------- K2: claim slots via CAS + zero cnt ----------------
__global__ __launch_bounds__(256) void k_claim(const int* __restrict__ s_idx,
                                               const int* __restrict__ p_idx,
                                               const int* __restrict__ n_idx,
                                               int* __restrict__ slot,
                                               int* __restrict__ cnt) {
    int i = blockIdx.x * 256 + threadIdx.x;   // 0 .. NSLOT-1
    cnt[i] = 0;
    int t = i >> 12;
    int q = i & (Q - 1);
    int node = (t == 0 ? s_idx : (t == 1 ? p_idx : n_idx))[q];
    atomicCAS(&slot[node], -1, i);
}

// ---------------- K3: build per-slot edge lists (int2 = {e, td}) -------
__global__ __launch_bounds__(256) void k_build(
    const int* __restrict__ src, const int* __restrict__ dst,
    const float* __restrict__ bt, const float* __restrict__ node_ts,
    const int* __restrict__ slot, int* __restrict__ cnt,
    int2* __restrict__ edata) {
    int e = blockIdx.x * 256 + threadIdx.x;
    if (e >= N_EDGES) return;
    int sl = slot[dst[e]];
    if (sl < 0) return;
    float td = bt[e] - node_ts[src[e]];
    int pos = atomicAdd(&cnt[sl], 1);
    if (pos < CAP) edata[sl * CAP + pos] = make_int2(e, __float_as_int(td));
}

// ---------------- K4: fused emb-build + predictor ----------------
// 512 blocks x 256 threads (4 waves), 8 queries per block.
// Phase A: unchanged (R16-18 proven).
// Phase B: thread = 4 queries x 8 cols; k split 8 ways (ksl in-wave x ksh
//   across wave-pairs); W k-tiles staged in LDS with XOR swizzle.
__global__ __launch_bounds__(256) void k_fused(
    const int* __restrict__ s_idx, const int* __restrict__ p_idx,
    const int* __restrict__ n_idx, const int* __restrict__ slot,
    const int* __restrict__ cnt, const int2* __restrict__ edata,
    const float* __restrict__ ef,
    const float* __restrict__ time_w, const float* __restrict__ time_b,
    const float* __restrict__ W_src, const float* __restrict__ b_src,
    const float* __restrict__ W_dst, const float* __restrict__ b_dst,
    const float* __restrict__ W_out, const float* __restrict__ b_out,
    float* __restrict__ out) {
    __shared__ float emb[QPB * 3][EMB_LD];   // ~25 KB (re-used as merge overlay)
    __shared__ float wstage[2][KT][HID];     // 32 KB
    const int tid   = threadIdx.x;
    const int qbase = blockIdx.x * QPB;
    const int wv    = tid >> 6;
    const int lane  = tid & 63;

    // ---- Phase A: lane-parallel gather (verbatim from R18) ----
    {
        const int j = lane >> 4;
        const int g = lane & 15;
        const float4 tw0 = *reinterpret_cast<const float4*>(time_w + 8 * g);
        const float4 tw1 = *reinterpret_cast<const float4*>(time_w + 8 * g + 4);
        const float4 tb0 = *reinterpret_cast<const float4*>(time_b + 8 * g);
        const float4 tb1 = *reinterpret_cast<const float4*>(time_b + 8 * g + 4);
        for (int row = wv; row < QPB * 3; row += 4) {
            int t = row >> 3, q = row & 7;
            const int* ia = (t == 0) ? s_idx : (t == 1) ? p_idx : n_idx;
            int sl = slot[ia[qbase + q]];
            int n = cnt[sl]; if (n > CAP) n = CAP;
            float4 accA = {0.f, 0.f, 0.f, 0.f}, accB = {0.f, 0.f, 0.f, 0.f};
            float4 tcA  = {0.f, 0.f, 0.f, 0.f}, tcB  = {0.f, 0.f, 0.f, 0.f};
            for (int jb = j; jb < n; jb += 4) {
                int2 ed = edata[(size_t)sl * CAP + jb];
                const float* rp = ef + (size_t)ed.x * 128;
                float4 vA = *reinterpret_cast<const float4*>(rp + 4 * g);
                float4 vB = *reinterpret_cast<const float4*>(rp + 64 + 4 * g);
                float td = __int_as_float(ed.y);
                accA.x += vA.x; accA.y += vA.y; accA.z += vA.z; accA.w += vA.w;
                accB.x += vB.x; accB.y += vB.y; accB.z += vB.z; accB.w += vB.w;
                tcA.x += __cosf(td * tw0.x + tb0.x);
                tcA.y += __cosf(td * tw0.y + tb0.y);
                tcA.z += __cosf(td * tw0.z + tb0.z);
                tcA.w += __cosf(td * tw0.w + tb0.w);
                tcB.x += __cosf(td * tw1.x + tb1.x);
                tcB.y += __cosf(td * tw1.y + tb1.y);
                tcB.z += __cosf(td * tw1.z + tb1.z);
                tcB.w += __cosf(td * tw1.w + tb1.w);
            }
#define RED2(v) { v += __shfl_xor(v, 16); v += __shfl_xor(v, 32); }
            RED2(accA.x) RED2(accA.y) RED2(accA.z) RED2(accA.w)
            RED2(accB.x) RED2(accB.y) RED2(accB.z) RED2(accB.w)
            RED2(tcA.x)  RED2(tcA.y)  RED2(tcA.z)  RED2(tcA.w)
            RED2(tcB.x)  RED2(tcB.y)  RED2(tcB.z)  RED2(tcB.w)
#undef RED2
            if (j == 0) {
                *reinterpret_cast<float4*>(&emb[row][4 * g])       = accA;
                *reinterpret_cast<float4*>(&emb[row][64 + 4 * g])  = accB;
                *reinterpret_cast<float4*>(&emb[row][128 + 8 * g]) = tcA;
                *reinterpret_cast<float4*>(&emb[row][132 + 8 * g]) = tcB;
            }
        }
    }

    // ---- Phase B: thread = 4 queries x 8 cols; k split 8 ways ----
    const int g3      = tid & 15;         // colgroup: cols [g3*8, g3*8+8)
    const int ksl     = (tid >> 4) & 3;   // in-wave k-sub
    const int qg      = wv & 1;           // queries qg*4 .. qg*4+3
    const int ksh     = wv >> 1;          // wave-pair k-half
    const int ks      = ksh * 4 + ksl;    // k-slice 0..7
    const int colbase = g3 * 8;

    float aS[4][8], aP[4][8], aN[4][8];
    #pragma unroll
    for (int qi = 0; qi < 4; ++qi)
        #pragma unroll
        for (int c = 0; c < 8; ++c) { aS[qi][c] = 0.f; aP[qi][c] = 0.f; aN[qi][c] = 0.f; }
    if (ks == 0) {
        #pragma unroll
        for (int c = 0; c < 8; ++c) {
            float bs = b_src[colbase + c], bd = b_dst[colbase + c];
            #pragma unroll
            for (int qi = 0; qi < 4; ++qi) { aS[qi][c] = bs; aP[qi][c] = bd; aN[qi][c] = bd; }
        }
    }

    const int kb = ks * 4;                // tile-local k-row base for this thread
    const int u0 = (g3 * 2) ^ ksl;        // swizzled float4-unit of cols [colbase, +4)
    const int u1 = (g3 * 2 + 1) ^ ksl;    // swizzled unit of cols [colbase+4, +8)

    for (int kt = 0; kt < DIN; kt += KT) {
        __syncthreads();   // Phase A done (kt=0) / previous tile consumed
        // stage W_src/W_dst[kt:kt+KT][0:128] with unit-XOR swizzle
        for (int r = tid; r < 2 * KT * HID / 4; r += 256) {
            int mat = r >> 10;
            int rem = r & 1023;
            int k   = rem >> 5;           // 0..31 tile-local
            int c4  = rem & 31;           // logical float4 unit
            const float* Wp = mat ? W_dst : W_src;
            float4 v = *reinterpret_cast<const float4*>(
                Wp + (size_t)(kt + k) * HID + c4 * 4);
            int c4s = c4 ^ ((k >> 2) & 3);
            *reinterpret_cast<float4*>(&wstage[mat][k][c4s * 4]) = v;
        }
        __syncthreads();

        // emb fragments for this thread's 4 k-rows (broadcast reads)
        float4 es[4], ep[4], en[4];
        #pragma unroll
        for (int qi = 0; qi < 4; ++qi) {
            int qrow = qg * 4 + qi;
            es[qi] = *reinterpret_cast<const float4*>(&emb[qrow][kt + kb]);
            ep[qi] = *reinterpret_cast<const float4*>(&emb[QPB + qrow][kt + kb]);
            en[qi] = *reinterpret_cast<const float4*>(&emb[2 * QPB + qrow][kt + kb]);
        }
        #pragma unroll
        for (int kk = 0; kk < 4; ++kk) {
            int k = kb + kk;
            float4 ws0 = *reinterpret_cast<const float4*>(&wstage[0][k][u0 * 4]);
            float4 ws1 = *reinterpret_cast<const float4*>(&wstage[0][k][u1 * 4]);
            float4 wd0 = *reinterpret_cast<const float4*>(&wstage[1][k][u0 * 4]);
            float4 wd1 = *reinterpret_cast<const float4*>(&wstage[1][k][u1 * 4]);
            #pragma unroll
            for (int qi = 0; qi < 4; ++qi) {
                float sv = (&es[qi].x)[kk];
                float pv = (&ep[qi].x)[kk];
                float nv = (&en[qi].x)[kk];
                #pragma unroll
                for (int c = 0; c < 4; ++c) {
                    aS[qi][c]     += sv * (&ws0.x)[c];
                    aS[qi][4 + c] += sv * (&ws1.x)[c];
                    aP[qi][c]     += pv * (&wd0.x)[c];
                    aP[qi][4 + c] += pv * (&wd1.x)[c];
                    aN[qi][c]     += nv * (&wd0.x)[c];
                    aN[qi][4 + c] += nv * (&wd1.x)[c];
                }
            }
        }
    }

    // ---- merge: in-wave over ksl, then cross ksh via LDS overlay ----
    #pragma unroll
    for (int qi = 0; qi < 4; ++qi)
        #pragma unroll
        for (int c = 0; c < 8; ++c) {
            float s = aS[qi][c]; s += __shfl_xor(s, 16); s += __shfl_xor(s, 32); aS[qi][c] = s;
            float p = aP[qi][c]; p += __shfl_xor(p, 16); p += __shfl_xor(p, 32); aP[qi][c] = p;
            float n = aN[qi][c]; n += __shfl_xor(n, 16); n += __shfl_xor(n, 32); aN[qi][c] = n;
        }

    float* ov = &emb[0][0];               // overlay: 32 slots x 97 floats (12.4 KB)
    __syncthreads();                      // all emb reads complete
    if (ksh == 1 && ksl == 0) {
        float* p = ov + (qg * 16 + g3) * 97;
        #pragma unroll
        for (int qi = 0; qi < 4; ++qi)
            #pragma unroll
            for (int c = 0; c < 8; ++c) {
                p[qi * 24 + c]      = aS[qi][c];
                p[qi * 24 + 8 + c]  = aP[qi][c];
                p[qi * 24 + 16 + c] = aN[qi][c];
            }
    }
    __syncthreads();
    if (ksh == 0 && ksl == 0) {
        const float* p = ov + (qg * 16 + g3) * 97;
        float4 wo0 = *reinterpret_cast<const float4*>(W_out + colbase);
        float4 wo1 = *reinterpret_cast<const float4*>(W_out + colbase + 4);
        float rP[4], rN[4];
        #pragma unroll
        for (int qi = 0; qi < 4; ++qi) {
            float sp = 0.f, sn = 0.f;
            #pragma unroll
            for (int c = 0; c < 8; ++c) {
                float sc = aS[qi][c] + p[qi * 24 + c];
                float pc = aP[qi][c] + p[qi * 24 + 8 + c];
                float nc = aN[qi][c] + p[qi * 24 + 16 + c];
                float woc = (c < 4) ? (&wo0.x)[c] : (&wo1.x)[c - 4];
                sp += fmaxf(sc + pc, 0.f) * woc;
                sn += fmaxf(sc + nc, 0.f) * woc;
            }
            rP[qi] = sp; rN[qi] = sn;
        }
        #pragma unroll
        for (int off = 1; off < 16; off <<= 1) {
            #pragma unroll
            for (int qi = 0; qi < 4; ++qi) {
                rP[qi] += __shfl_xor(rP[qi], off);
                rN[qi] += __shfl_xor(rN[qi], off);
            }
        }
        if (g3 == 0) {
            float bo = b_out[0];
            #pragma unroll
            for (int qi = 0; qi < 4; ++qi) {
                out[qbase + qg * 4 + qi]     = rP[qi] + bo;
                out[Q + qbase + qg * 4 + qi] = rN[qi] + bo;
            }
        }
    }
}

// ---------------- launch ----------------

extern "C" void kernel_launch(void* const* d_in, const int* in_sizes, int n_in,
                              void* d_out, int out_size, void* d_ws, size_t ws_size,
                              hipStream_t stream) {
    const int*   src     = (const int*)d_in[0];
    const int*   dst     = (const int*)d_in[1];
    const float* ef      = (const float*)d_in[2];
    const float* bt      = (const float*)d_in[3];
    const float* node_ts = (const float*)d_in[4];
    const int*   s_idx   = (const int*)d_in[5];
    const int*   p_idx   = (const int*)d_in[6];
    const int*   n_idx   = (const int*)d_in[7];
    const float* time_w  = (const float*)d_in[8];
    const float* time_b  = (const float*)d_in[9];
    const float* W_src   = (const float*)d_in[10];
    const float* b_src   = (const float*)d_in[11];
    const float* W_dst   = (const float*)d_in[12];
    const float* b_dst   = (const float*)d_in[13];
    const float* W_out   = (const float*)d_in[14];
    const float* b_out   = (const float*)d_in[15];
    float*       out     = (float*)d_out;

    // workspace layout (bytes)
    char* ws = (char*)d_ws;
    int*   slot  = (int*)ws;                          // [100000]
    int*   cnt   = (int*)(ws + 512 * 1024);           // [12288]
    int2*  edata = (int2*)(ws + 1024 * 1024);         // [12288*64] int2 = 6.3 MB

    k_init<<<(N_NODES / 4 + 255) / 256, 256, 0, stream>>>((int4*)slot);
    k_claim<<<NSLOT / 256, 256, 0, stream>>>(s_idx, p_idx, n_idx, slot, cnt);
    k_build<<<(N_EDGES + 255) / 256, 256, 0, stream>>>(src, dst, bt, node_ts,
                                                       slot, cnt, edata);
    k_fused<<<Q / QPB, 256, 0, stream>>>(s_idx, p_idx, n_idx, slot, cnt,
                                         edata, ef, time_w, time_b,
                                         W_src, b_src, W_dst, b_dst,
                                         W_out, b_out, out);
}